// Round 8
// baseline (333.760 us; speedup 1.0000x reference)
//
#include <hip/hip_runtime.h>

#define N_NODES 50000
#define N_EDGES 800000
#define IN_F    128
#define HID_F   304
#define NTILES  19      // 304 / 16
#define NBK     49      // buckets per graph (1024 nodes each)
#define BKN     1024    // nodes per bucket
#define CAP_B   18432   // edges per bucket: mean 16384, sigma ~127 -> +16 sigma
#define CHUNK   4096    // edges per phase-A block
#define NCHUNK  196     // ceil(800000 / 4096)
#define NTB     782     // ceil(50000 / 64) node tiles per graph
#define IDXS    64      // staged indices per row (Poisson(16); deg>64 ~ never, slow tail path)
#define DUMMY   ((ushort_t)N_NODES)          // index of the zero row
#define GSTRIDE ((size_t)(N_NODES + 1) * 128)  // fp8 bytes per graph incl. dummy row

typedef unsigned int   uint_t;
typedef unsigned short ushort_t;
typedef unsigned char  uchar_t;
typedef __attribute__((ext_vector_type(8))) short          short8_t;
typedef __attribute__((ext_vector_type(8))) unsigned short ushort8_t;
typedef __attribute__((ext_vector_type(4))) float          floatx4;
typedef __attribute__((ext_vector_type(2))) float          floatx2;

__device__ inline float bf2f(uint_t h) {
    uint_t u = h << 16; float f; __builtin_memcpy(&f, &u, 4); return f;
}
__device__ inline ushort_t f2bf(float f) {
    uint_t u; __builtin_memcpy(&u, &f, 4);
    uint_t r = u + 0x7fffu + ((u >> 16) & 1u);   // RTNE
    return (ushort_t)(r >> 16);
}
__device__ inline uint_t packbf2(float a, float b) {
    return (uint_t)f2bf(a) | ((uint_t)f2bf(b) << 16);
}

// ---- fp8 e4m3 (OCP) encode/decode, HW builtins with SW fallback ----
__device__ inline uint_t f8enc1(float f) {
    uint_t u; __builtin_memcpy(&u, &f, 4);
    uint_t s = (u >> 24) & 0x80u;
    float a = fabsf(f);
    if (a >= 448.f) return s | 0x7Eu;
    uint_t mag = u & 0x7fffffffu;
    uint_t r = mag + 0x7ffffu + ((mag >> 20) & 1u);
    int e8 = (int)(r >> 23) - 120;
    if (e8 <= 0) { int k = (int)rintf(a * 512.f); return s | (uint_t)k; }
    if (e8 > 15) return s | 0x7Eu;
    return s | ((uint_t)e8 << 3) | ((r >> 20) & 7u);
}
__device__ inline float f8dec1(uint_t b) {
    uint_t s = (b & 0x80u) << 24;
    uint_t e = (b >> 3) & 0xFu, m = b & 7u;
    uint_t bits;
    if (e == 0) {
        float v = (float)m * 0.001953125f;
        uint_t vb; __builtin_memcpy(&vb, &v, 4);
        bits = vb | s;
    } else {
        bits = s | ((e + 120u) << 23) | (m << 20);
    }
    float f; __builtin_memcpy(&f, &bits, 4); return f;
}
__device__ inline uint_t f8pack4(float a, float b, float c, float d) {
#if __has_builtin(__builtin_amdgcn_cvt_pk_fp8_f32)
    int v = __builtin_amdgcn_cvt_pk_fp8_f32(a, b, 0, false);
    v = __builtin_amdgcn_cvt_pk_fp8_f32(c, d, v, true);
    return (uint_t)v;
#else
    return f8enc1(a) | (f8enc1(b) << 8) | (f8enc1(c) << 16) | (f8enc1(d) << 24);
#endif
}
__device__ inline floatx2 f8dec2lo(uint_t v) {
#if __has_builtin(__builtin_amdgcn_cvt_pk_f32_fp8)
    return __builtin_amdgcn_cvt_pk_f32_fp8((int)v, false);
#else
    floatx2 r; r.x = f8dec1(v & 0xffu); r.y = f8dec1((v >> 8) & 0xffu); return r;
#endif
}
__device__ inline floatx2 f8dec2hi(uint_t v) {
#if __has_builtin(__builtin_amdgcn_cvt_pk_f32_fp8)
    return __builtin_amdgcn_cvt_pk_f32_fp8((int)v, true);
#else
    floatx2 r; r.x = f8dec1((v >> 16) & 0xffu); r.y = f8dec1((v >> 24) & 0xffu); return r;
#endif
}

// ---------------- phase A: partition edges into 49 dst-buckets; deg_out via 8-sliced atomics ----------------
__global__ __launch_bounds__(256) void k_bucket(
        const int* __restrict__ s0, const int* __restrict__ d0,
        const int* __restrict__ s1, const int* __restrict__ d1,
        const int* __restrict__ s2, const int* __restrict__ d2,
        int* __restrict__ alloc_d, int* __restrict__ deg8, uint_t* __restrict__ region_d) {
    __shared__ int hist_d[NBK], lcur_d[NBK];
    int tid = threadIdx.x;
    int g = blockIdx.x / NCHUNK;
    int chunk = blockIdx.x - g * NCHUNK;
    int slice = (g * 8 + (blockIdx.x & 7)) * N_NODES;   // %8 ~ XCD-local L2 lines
    const int* sp = (g == 0) ? s0 : ((g == 1) ? s1 : s2);
    const int* dp = (g == 0) ? d0 : ((g == 1) ? d1 : d2);
    int base = chunk * CHUNK;
    int cnt = N_EDGES - base; if (cnt > CHUNK) cnt = CHUNK;

    if (tid < NBK) hist_d[tid] = 0;
    __syncthreads();
    for (int i = tid; i < cnt; i += 256)
        atomicAdd(&hist_d[dp[base + i] >> 10], 1);
    __syncthreads();
    if (tid < NBK) {
        int cd = hist_d[tid];
        lcur_d[tid] = cd ? atomicAdd(&alloc_d[g * NBK + tid], cd) : 0;
    }
    __syncthreads();
    for (int i = tid; i < cnt; i += 256) {
        int d = dp[base + i];
        int s = sp[base + i];
        int bd = d >> 10;
        int slot = atomicAdd(&lcur_d[bd], 1);
        if (slot < CAP_B)
            region_d[(size_t)(g * NBK + bd) * CAP_B + slot] = (uint_t)s | ((uint_t)(d & 1023) << 16);
        atomicAdd(&deg8[slice + s], 1);
    }
}

// ---------------- phase B: per-bucket counting sort -> ushort CSR + row_off/deg_in ----------------
__global__ __launch_bounds__(256) void k_sortcsr(const uint_t* __restrict__ region_d,
                                                 const int* __restrict__ alloc_d,
                                                 int* __restrict__ row_off,
                                                 int* __restrict__ deg_in,
                                                 ushort_t* __restrict__ csr16) {
    __shared__ int cnt_s[BKN];
    __shared__ int off_s[BKN];
    __shared__ int wsum[4];
    int tid = threadIdx.x, lane = tid & 63, wv = tid >> 6;
    int g = blockIdx.x / NBK;
    int b = blockIdx.x - g * NBK;
    int cnt = alloc_d[g * NBK + b]; if (cnt > CAP_B) cnt = CAP_B;
    const uint_t* reg = region_d + (size_t)(g * NBK + b) * CAP_B;
    int bucket_base = (g * NBK + b) * CAP_B;
    int node0 = b * BKN;
    int nb = N_NODES - node0; if (nb > BKN) nb = BKN;

    for (int i = tid; i < BKN; i += 256) cnt_s[i] = 0;
    __syncthreads();
    for (int i = tid; i < cnt; i += 256)
        atomicAdd(&cnt_s[reg[i] >> 16], 1);
    __syncthreads();

    int c0 = cnt_s[tid * 4], c1 = cnt_s[tid * 4 + 1], c2 = cnt_s[tid * 4 + 2], c3 = cnt_s[tid * 4 + 3];
    int tsum = c0 + c1 + c2 + c3;
    int inc = tsum;
    #pragma unroll
    for (int o = 1; o < 64; o <<= 1) {
        int u = __shfl_up(inc, o, 64);
        if (lane >= o) inc += u;
    }
    if (lane == 63) wsum[wv] = inc;
    __syncthreads();
    int woff = 0;
    if (wv > 0) woff = wsum[0];
    if (wv > 1) woff += wsum[1];
    if (wv > 2) woff += wsum[2];
    int e0 = woff + inc - tsum;
    off_s[tid * 4]     = e0;
    off_s[tid * 4 + 1] = e0 + c0;
    off_s[tid * 4 + 2] = e0 + c0 + c1;
    off_s[tid * 4 + 3] = e0 + c0 + c1 + c2;
    __syncthreads();

    for (int i = tid; i < nb; i += 256) {
        row_off[g * N_NODES + node0 + i] = bucket_base + off_s[i];
        deg_in [g * N_NODES + node0 + i] = cnt_s[i];
    }
    __syncthreads();

    for (int i = tid; i < cnt; i += 256) {
        uint_t w = reg[i];
        int dl = (int)(w >> 16);
        int pos = atomicAdd(&off_s[dl], 1);
        csr16[bucket_base + pos] = (ushort_t)(w & 0xffffu);
    }
}

// ---------------- prescale (all 3 graphs + dummy rows): xs = fp8(x * inv_out * 16) ----------------
__global__ void k_prescale_all(const float* __restrict__ x0, const float* __restrict__ x1,
                               const float* __restrict__ x2, const int* __restrict__ deg8,
                               uchar_t* __restrict__ xs3) {
    int gid = blockIdx.x * 256 + threadIdx.x;   // 3*(N+1)*16 groups of 8 features
    if (gid >= 3 * (N_NODES + 1) * 16) return;
    int g = gid / ((N_NODES + 1) * 16);
    int loc = gid - g * (N_NODES + 1) * 16;
    int n = loc >> 4, c = loc & 15;
    uchar_t* outp = xs3 + (size_t)g * GSTRIDE + (size_t)n * 128 + c * 8;
    if (n == N_NODES) {                          // dummy zero row
        *(uint2*)outp = make_uint2(0u, 0u);
        return;
    }
    const int* d8 = deg8 + g * 8 * N_NODES + n;
    int d = 0;
    #pragma unroll
    for (int c8 = 0; c8 < 8; c8++) d += d8[c8 * N_NODES];
    if (d < 1) d = 1;
    const float* x = (g == 0) ? x0 : ((g == 1) ? x1 : x2);
    float s = rsqrtf((float)d) * 16.f;           // x16 exact, undone in gather
    const float4* xp = (const float4*)(x + n * 128 + c * 8);
    float4 v0 = xp[0], v1 = xp[1];
    uint2 o;
    o.x = f8pack4(v0.x * s, v0.y * s, v0.z * s, v0.w * s);
    o.y = f8pack4(v1.x * s, v1.y * s, v1.z * s, v1.w * s);
    *(uint2*)outp = o;
}

// ---------------- pack W into B-fragment layout (bf16), once ----------------
__global__ void k_prepW(const float* __restrict__ W, ushort_t* __restrict__ Wp) {
    int gid = blockIdx.x * 256 + threadIdx.x;   // NTILES*4*64 = 4864 groups
    if (gid >= NTILES * 4 * 64) return;
    int ct   = gid >> 8;
    int rem  = gid & 255;
    int kk   = rem >> 6;
    int lane = rem & 63;
    int col   = ct * 16 + (lane & 15);
    int kbase = kk * 32 + (lane >> 4) * 8;
    uint_t o[4];
    #pragma unroll
    for (int p = 0; p < 4; p++) {
        float f0 = W[(kbase + 2 * p)     * HID_F + col];
        float f1 = W[(kbase + 2 * p + 1) * HID_F + col];
        o[p] = packbf2(f0, f1);
    }
    *(uint4*)(Wp + gid * 8) = make_uint4(o[0], o[1], o[2], o[3]);
}

// ---------------- fused paired-row gather (fp8 dword loads) + MFMA GEMM ----------------
#define TSTRIDE 136   // 128 + 8 bf16 pad
__global__ __launch_bounds__(256, 4) void k_gg(const uchar_t* __restrict__ xs3,
                                               const int* __restrict__ row_off,
                                               const int* __restrict__ deg_in,
                                               const ushort_t* __restrict__ csr16,
                                               const ushort_t* __restrict__ Wp,
                                               const float* __restrict__ bias,
                                               float* __restrict__ gsum) {
    __shared__ ushort_t t_s[64 * TSTRIDE];          // 17408 B
    __shared__ ushort_t idx_s[4 * 16 * IDXS];       // 8192 B
    __shared__ float b_s[HID_F];
    __shared__ float wred[4];

    int tid = threadIdx.x, lane = tid & 63, wv = tid >> 6;
    int bid = blockIdx.x;
    int g = bid / NTB;
    int tile = bid - g * NTB;
    int n0 = tile * 64;
    int nfirst = n0 + wv * 16;
    bool wvalid = (nfirst + 16 <= N_NODES);   // 50000 % 64 == 16: waves all-valid or all-invalid

    const uchar_t* xb = xs3 + (size_t)g * GSTRIDE;
    const int* ro = row_off + g * N_NODES;
    const int* di = deg_in + g * N_NODES;

    if (tid < HID_F / 4) ((float4*)b_s)[tid] = ((const float4*)bias)[tid];

    int offv = 0, degv = 0;
    if (wvalid) {
        int node_l = nfirst + (lane & 15);
        offv = ro[node_l];        // lane l holds row (l & 15)
        degv = di[node_l];
    }

    int half = lane >> 5;               // 0: row A of pair, 1: row B
    int feat_off = (lane & 31) * 4;     // 4 fp8 features per lane

    if (wvalid) {
        // ---- stage indices: 4 lanes per row, strided copy ----
        {
            int row = lane >> 2, t4 = lane & 3;
            int o_r = __shfl(offv, row);
            int d_r = __shfl(degv, row);
            int dcap = d_r < IDXS ? d_r : IDXS;
            ushort_t* dst = idx_s + (wv * 16 + row) * IDXS;
            for (int j = t4; j < dcap; j += 4) dst[j] = csr16[o_r + j];
        }
        // ---- pad each row to its pair bound with DUMMY ----
        if (lane < 16) {
            int d_r = degv;
            int d_p = __shfl(degv, lane ^ 1);
            int mx = d_r > d_p ? d_r : d_p;
            int bnd = (mx + 7) & ~7; if (bnd > IDXS) bnd = IDXS;
            int st = d_r < IDXS ? d_r : IDXS;
            ushort_t* dst = idx_s + (wv * 16 + lane) * IDXS;
            for (int j = st; j < bnd; j++) dst[j] = DUMMY;
        }

        uint_t* trow = (uint_t*)t_s;
        #pragma unroll 2
        for (int pg = 0; pg < 2; pg++) {
            int b_k[4], dm_k[4];
            #pragma unroll
            for (int k = 0; k < 4; k++) {
                int da = __builtin_amdgcn_readlane(degv, pg * 8 + 2 * k);
                int db = __builtin_amdgcn_readlane(degv, pg * 8 + 2 * k + 1);
                int mx = da > db ? da : db;
                dm_k[k] = mx;
                int bnd = (mx + 7) & ~7; if (bnd > IDXS) bnd = IDXS;
                b_k[k] = bnd;
            }
            int gmax = b_k[0];
            if (b_k[1] > gmax) gmax = b_k[1];
            if (b_k[2] > gmax) gmax = b_k[2];
            if (b_k[3] > gmax) gmax = b_k[3];

            float a[4][4] = {{0.f,0.f,0.f,0.f},{0.f,0.f,0.f,0.f},{0.f,0.f,0.f,0.f},{0.f,0.f,0.f,0.f}};

            for (int j = 0; j < gmax; j += 8) {
                uint_t vv[4][8];
                ushort8_t inds[4];
                // issue all loads first (up to 32 outstanding, 256 B each)
                #pragma unroll
                for (int k = 0; k < 4; k++) {
                    if (j < b_k[k]) {
                        inds[k] = *(const ushort8_t*)(idx_s + (wv * 16 + pg * 8 + 2 * k + half) * IDXS + j);
                        #pragma unroll
                        for (int e = 0; e < 8; e++) {
                            int idx = (int)inds[k][e];
                            vv[k][e] = *(const uint_t*)(xb + (size_t)idx * 128 + feat_off);
                        }
                    }
                }
                // consume
                #pragma unroll
                for (int k = 0; k < 4; k++) {
                    if (j < b_k[k]) {
                        #pragma unroll
                        for (int e = 0; e < 8; e++) {
                            uint_t v = vv[k][e];
                            floatx2 lo = f8dec2lo(v);
                            floatx2 hi = f8dec2hi(v);
                            a[k][0] += lo.x; a[k][1] += lo.y;
                            a[k][2] += hi.x; a[k][3] += hi.y;
                        }
                    }
                }
            }

            // epilogue per pair (+ never-taken tail for deg > IDXS)
            #pragma unroll
            for (int k = 0; k < 4; k++) {
                int r = pg * 8 + 2 * k + half;      // lane's row within wave
                int d_r = __shfl(degv, r);
                if (dm_k[k] > IDXS) {                // astronomically rare; correctness path
                    int o_r = __shfl(offv, r);
                    for (int j = IDXS; j < dm_k[k]; j++) {
                        int pc = j < d_r ? j : (d_r > 0 ? d_r - 1 : 0);
                        int idx = (int)csr16[o_r + pc];
                        uint_t v = *(const uint_t*)(xb + (size_t)idx * 128 + feat_off);
                        if (j >= d_r) v = 0u;
                        floatx2 lo = f8dec2lo(v);
                        floatx2 hi = f8dec2hi(v);
                        a[k][0] += lo.x; a[k][1] += lo.y;
                        a[k][2] += hi.x; a[k][3] += hi.y;
                    }
                }
                int dd = d_r < 1 ? 1 : d_r;
                float sc = rsqrtf((float)dd) * 0.0625f;   // undo x16 prescale
                uint2 o;
                o.x = packbf2(a[k][0] * sc, a[k][1] * sc);
                o.y = packbf2(a[k][2] * sc, a[k][3] * sc);
                *(uint2*)((char*)t_s + (size_t)(wv * 16 + r) * TSTRIDE * 2 + (lane & 31) * 8) = o;
            }
        }
    } else {
        for (int r = 0; r < 16; r++)
            *(uint2*)((char*)t_s + (size_t)(wv * 16 + r) * TSTRIDE * 2 + (lane & 31) * 8) = make_uint2(0u, 0u);
    }
    __syncthreads();

    int m = lane & 15, quad = lane >> 4;
    const ushort_t* ap = &t_s[(wv * 16 + m) * TSTRIDE + quad * 8];
    short8_t a0f = *(const short8_t*)(ap);
    short8_t a1f = *(const short8_t*)(ap + 32);
    short8_t a2f = *(const short8_t*)(ap + 64);
    short8_t a3f = *(const short8_t*)(ap + 96);

    float ssum = 0.f;
    int row_base = n0 + wv * 16 + quad * 4;

    for (int ct = 0; ct < NTILES; ct++) {
        const ushort_t* w0 = Wp + ((ct * 4) * 64 + lane) * 8;
        short8_t b0 = *(const short8_t*)(w0);
        short8_t b1 = *(const short8_t*)(w0 + 512);
        short8_t b2 = *(const short8_t*)(w0 + 1024);
        short8_t b3 = *(const short8_t*)(w0 + 1536);
        floatx4 acc = {0.f, 0.f, 0.f, 0.f};
        acc = __builtin_amdgcn_mfma_f32_16x16x32_bf16(a0f, b0, acc, 0, 0, 0);
        acc = __builtin_amdgcn_mfma_f32_16x16x32_bf16(a1f, b1, acc, 0, 0, 0);
        acc = __builtin_amdgcn_mfma_f32_16x16x32_bf16(a2f, b2, acc, 0, 0, 0);
        acc = __builtin_amdgcn_mfma_f32_16x16x32_bf16(a3f, b3, acc, 0, 0, 0);
        float bv = b_s[ct * 16 + m];
        #pragma unroll
        for (int r = 0; r < 4; r++) {
            if (row_base + r < N_NODES) {
                float y = acc[r] + bv;        // C/D: col=lane&15, row=quad*4+r
                ssum += fmaxf(y, 0.f);
            }
        }
    }

    #pragma unroll
    for (int o = 32; o; o >>= 1) ssum += __shfl_down(ssum, o, 64);
    if (lane == 0) wred[wv] = ssum;
    __syncthreads();
    if (tid == 0) atomicAdd(gsum, wred[0] + wred[1] + wred[2] + wred[3]);
}

// ---------------- finalize ----------------
__global__ void k_finalize(const float* __restrict__ gsum, float* __restrict__ out) {
    out[0] = gsum[0] * (1.0f / (3.0f * N_NODES * HID_F));
}

extern "C" void kernel_launch(void* const* d_in, const int* in_sizes, int n_in,
                              void* d_out, int out_size, void* d_ws, size_t ws_size,
                              hipStream_t stream) {
    const float* x0 = (const float*)d_in[0];
    const float* x1 = (const float*)d_in[1];
    const float* x2 = (const float*)d_in[2];
    const int* srcs[3] = {(const int*)d_in[3], (const int*)d_in[5], (const int*)d_in[7]};
    const int* dsts[3] = {(const int*)d_in[4], (const int*)d_in[6], (const int*)d_in[8]};
    const float* W = (const float*)d_in[9];
    const float* b = (const float*)d_in[10];

    char* ws = (char*)d_ws;
    int* deg8        = (int*)(ws + 0);                 // 4,800,000 (8 slices x 3 graphs)
    int* alloc_d     = (int*)(ws + 4800000);           // 588 (pad to 640)
    int* deg_in      = (int*)(ws + 4800640);           // 600,000
    int* row_off     = (int*)(ws + 5400640);           // 600,000
    ushort_t* csr16  = (ushort_t*)(ws + 6000640);      // 5,419,008 -> ends 11,419,648
    uint_t* region_d = (uint_t*)(ws + 11419648);       // 10,838,016 (dead after sortcsr)
    uchar_t* xs3     = (uchar_t*)(ws + 11419648);      // 19,200,384 fp8 (overlays region_d)
    ushort_t* Wp     = (ushort_t*)(ws + 30620032);     // 77,824
    float* gsum      = (float*)(ws + 30697856);        // 4

    hipMemsetAsync(deg8, 0, 4800640, stream);          // deg8 + alloc_d contiguous
    hipMemsetAsync(gsum, 0, 4, stream);

    k_prepW<<<(NTILES * 4 * 64 + 255) / 256, 256, 0, stream>>>(W, Wp);
    k_bucket<<<3 * NCHUNK, 256, 0, stream>>>(
        srcs[0], dsts[0], srcs[1], dsts[1], srcs[2], dsts[2],
        alloc_d, deg8, region_d);
    k_sortcsr<<<3 * NBK, 256, 0, stream>>>(
        region_d, alloc_d, row_off, deg_in, csr16);
    k_prescale_all<<<(3 * (N_NODES + 1) * 16 + 255) / 256, 256, 0, stream>>>(
        x0, x1, x2, deg8, xs3);
    k_gg<<<3 * NTB, 256, 0, stream>>>(xs3, row_off, deg_in, csr16, Wp, b, gsum);
    k_finalize<<<1, 1, 0, stream>>>(gsum, (float*)d_out);
}

// Round 9
// 292.299 us; speedup vs baseline: 1.1418x; 1.1418x over previous
//
#include <hip/hip_runtime.h>

#define N_NODES 50000
#define N_EDGES 800000
#define IN_F    128
#define HID_F   304
#define NTILES  19      // 304 / 16
#define NBK     49      // buckets per graph (1024 nodes each)
#define BKN     1024    // nodes per bucket
#define CAP_B   18432   // csr16 entries per bucket (mean 16384, sigma 127, +16 sigma)
#define CHUNK   4096    // edges per phase-A block
#define NCH     196     // chunks per graph
#define CAP_C   160     // slots per (chunk, bucket) cell: mean 84, sigma 9.1, +8.4 sigma
#define NTB     782     // ceil(50000 / 64) node tiles per graph
#define IDXS    64      // staged indices per row in k_gg
#define DUMMY   ((ushort_t)N_NODES)            // index of the zero row
#define GSTRIDE ((size_t)(N_NODES + 1) * 128)  // fp8 bytes per graph incl. dummy row

typedef unsigned int   uint_t;
typedef unsigned short ushort_t;
typedef unsigned char  uchar_t;
typedef __attribute__((ext_vector_type(8))) short          short8_t;
typedef __attribute__((ext_vector_type(8))) unsigned short ushort8_t;
typedef __attribute__((ext_vector_type(4))) float          floatx4;
typedef __attribute__((ext_vector_type(2))) float          floatx2;

__device__ inline float bf2f(uint_t h) {
    uint_t u = h << 16; float f; __builtin_memcpy(&f, &u, 4); return f;
}
__device__ inline ushort_t f2bf(float f) {
    uint_t u; __builtin_memcpy(&u, &f, 4);
    uint_t r = u + 0x7fffu + ((u >> 16) & 1u);   // RTNE
    return (ushort_t)(r >> 16);
}
__device__ inline uint_t packbf2(float a, float b) {
    return (uint_t)f2bf(a) | ((uint_t)f2bf(b) << 16);
}

// ---- fp8 e4m3 (OCP) encode/decode, HW builtins with SW fallback ----
__device__ inline uint_t f8enc1(float f) {
    uint_t u; __builtin_memcpy(&u, &f, 4);
    uint_t s = (u >> 24) & 0x80u;
    float a = fabsf(f);
    if (a >= 448.f) return s | 0x7Eu;
    uint_t mag = u & 0x7fffffffu;
    uint_t r = mag + 0x7ffffu + ((mag >> 20) & 1u);
    int e8 = (int)(r >> 23) - 120;
    if (e8 <= 0) { int k = (int)rintf(a * 512.f); return s | (uint_t)k; }
    if (e8 > 15) return s | 0x7Eu;
    return s | ((uint_t)e8 << 3) | ((r >> 20) & 7u);
}
__device__ inline float f8dec1(uint_t b) {
    uint_t s = (b & 0x80u) << 24;
    uint_t e = (b >> 3) & 0xFu, m = b & 7u;
    uint_t bits;
    if (e == 0) {
        float v = (float)m * 0.001953125f;
        uint_t vb; __builtin_memcpy(&vb, &v, 4);
        bits = vb | s;
    } else {
        bits = s | ((e + 120u) << 23) | (m << 20);
    }
    float f; __builtin_memcpy(&f, &bits, 4); return f;
}
__device__ inline uint_t f8pack4(float a, float b, float c, float d) {
#if __has_builtin(__builtin_amdgcn_cvt_pk_fp8_f32)
    int v = __builtin_amdgcn_cvt_pk_fp8_f32(a, b, 0, false);
    v = __builtin_amdgcn_cvt_pk_fp8_f32(c, d, v, true);
    return (uint_t)v;
#else
    return f8enc1(a) | (f8enc1(b) << 8) | (f8enc1(c) << 16) | (f8enc1(d) << 24);
#endif
}
__device__ inline floatx2 f8dec2lo(uint_t v) {
#if __has_builtin(__builtin_amdgcn_cvt_pk_f32_fp8)
    return __builtin_amdgcn_cvt_pk_f32_fp8((int)v, false);
#else
    floatx2 r; r.x = f8dec1(v & 0xffu); r.y = f8dec1((v >> 8) & 0xffu); return r;
#endif
}
__device__ inline floatx2 f8dec2hi(uint_t v) {
#if __has_builtin(__builtin_amdgcn_cvt_pk_f32_fp8)
    return __builtin_amdgcn_cvt_pk_f32_fp8((int)v, true);
#else
    floatx2 r; r.x = f8dec1((v >> 16) & 0xffu); r.y = f8dec1((v >> 24) & 0xffu); return r;
#endif
}

// ---------------- phase A: fixed-slot partition (no hist pass, no global atomics) ----------------
__global__ __launch_bounds__(256) void k_bucket(
        const int* __restrict__ s0, const int* __restrict__ d0,
        const int* __restrict__ s1, const int* __restrict__ d1,
        const int* __restrict__ s2, const int* __restrict__ d2,
        int* __restrict__ cnt_d, int* __restrict__ cnt_sA,
        uint_t* __restrict__ region_d, ushort_t* __restrict__ region_s) {
    __shared__ int lcur_d[NBK], lcur_s[NBK];
    int tid = threadIdx.x;
    int g = blockIdx.x / NCH;
    int chunk = blockIdx.x - g * NCH;
    const int* sp = (g == 0) ? s0 : ((g == 1) ? s1 : s2);
    const int* dp = (g == 0) ? d0 : ((g == 1) ? d1 : d2);
    int base = chunk * CHUNK;
    int cnt = N_EDGES - base; if (cnt > CHUNK) cnt = CHUNK;
    int cell0 = (g * NCH + chunk) * NBK;

    if (tid < NBK) { lcur_d[tid] = 0; lcur_s[tid] = 0; }
    __syncthreads();
    for (int i = tid; i < cnt; i += 256) {
        int d = dp[base + i];
        int s = sp[base + i];
        int bd = d >> 10;
        int slot = atomicAdd(&lcur_d[bd], 1);
        if (slot < CAP_C)
            region_d[(size_t)(cell0 + bd) * CAP_C + slot] = (uint_t)s | ((uint_t)(d & 1023) << 16);
        int bs = s >> 10;
        int slot2 = atomicAdd(&lcur_s[bs], 1);
        if (slot2 < CAP_C)
            region_s[(size_t)(cell0 + bs) * CAP_C + slot2] = (ushort_t)(s & 1023);
    }
    __syncthreads();
    if (tid < NBK) {
        int cd = lcur_d[tid]; if (cd > CAP_C) cd = CAP_C;
        int cs = lcur_s[tid]; if (cs > CAP_C) cs = CAP_C;
        cnt_d [cell0 + tid] = cd;
        cnt_sA[cell0 + tid] = cs;
    }
}

// ---------------- phase B: 147 dst-CSR blocks + 147 src->deg_out blocks ----------------
__global__ __launch_bounds__(256) void k_csr(const uint_t* __restrict__ region_d,
                                             const ushort_t* __restrict__ region_s,
                                             const int* __restrict__ cnt_d,
                                             const int* __restrict__ cnt_sA,
                                             int* __restrict__ row_off,
                                             int* __restrict__ deg_in,
                                             int* __restrict__ deg_out,
                                             ushort_t* __restrict__ csr16) {
    __shared__ int hist[BKN];
    __shared__ int off_s[BKN];
    __shared__ int wsum[4];
    int tid = threadIdx.x, lane = tid & 63, wv = tid >> 6;
    int bid = blockIdx.x;
    bool dst_part = (bid < 3 * NBK);
    int lb = dst_part ? bid : bid - 3 * NBK;
    int g = lb / NBK;
    int b = lb - g * NBK;
    int node0 = b * BKN;
    int nb = N_NODES - node0; if (nb > BKN) nb = BKN;

    for (int i = tid; i < BKN; i += 256) hist[i] = 0;
    __syncthreads();

    if (dst_part) {
        // histogram of dst_local over this bucket's 196 runs
        for (int c = wv; c < NCH; c += 4) {
            int cell = (g * NCH + c) * NBK + b;
            int n = cnt_d[cell];
            const uint_t* src = region_d + (size_t)cell * CAP_C;
            for (int i = lane; i < n; i += 64)
                atomicAdd(&hist[src[i] >> 16], 1);
        }
        __syncthreads();

        // exclusive scan of 1024 counts (4 per thread)
        int c0 = hist[tid * 4], c1 = hist[tid * 4 + 1], c2 = hist[tid * 4 + 2], c3 = hist[tid * 4 + 3];
        int tsum = c0 + c1 + c2 + c3;
        int inc = tsum;
        #pragma unroll
        for (int o = 1; o < 64; o <<= 1) {
            int u = __shfl_up(inc, o, 64);
            if (lane >= o) inc += u;
        }
        if (lane == 63) wsum[wv] = inc;
        __syncthreads();
        int woff = 0;
        if (wv > 0) woff = wsum[0];
        if (wv > 1) woff += wsum[1];
        if (wv > 2) woff += wsum[2];
        int e0 = woff + inc - tsum;
        off_s[tid * 4]     = e0;
        off_s[tid * 4 + 1] = e0 + c0;
        off_s[tid * 4 + 2] = e0 + c0 + c1;
        off_s[tid * 4 + 3] = e0 + c0 + c1 + c2;
        __syncthreads();

        int bucket_base = (g * NBK + b) * CAP_B;
        for (int i = tid; i < nb; i += 256) {
            row_off[g * N_NODES + node0 + i] = bucket_base + off_s[i];
            deg_in [g * N_NODES + node0 + i] = hist[i];
        }
        __syncthreads();

        // scatter into bucket-local CSR
        for (int c = wv; c < NCH; c += 4) {
            int cell = (g * NCH + c) * NBK + b;
            int n = cnt_d[cell];
            const uint_t* src = region_d + (size_t)cell * CAP_C;
            for (int i = lane; i < n; i += 64) {
                uint_t w = src[i];
                int pos = atomicAdd(&off_s[w >> 16], 1);
                csr16[bucket_base + pos] = (ushort_t)(w & 0xffffu);
            }
        }
    } else {
        // histogram of src_local -> deg_out
        for (int c = wv; c < NCH; c += 4) {
            int cell = (g * NCH + c) * NBK + b;
            int n = cnt_sA[cell];
            const ushort_t* src = region_s + (size_t)cell * CAP_C;
            for (int i = lane; i < n; i += 64)
                atomicAdd(&hist[src[i]], 1);
        }
        __syncthreads();
        for (int i = tid; i < nb; i += 256)
            deg_out[g * N_NODES + node0 + i] = hist[i];
    }
}

// ---------------- prescale (all 3 graphs + dummy rows): xs = fp8(x * inv_out * 16) ----------------
__global__ void k_prescale_all(const float* __restrict__ x0, const float* __restrict__ x1,
                               const float* __restrict__ x2, const int* __restrict__ deg_out,
                               uchar_t* __restrict__ xs3) {
    int gid = blockIdx.x * 256 + threadIdx.x;   // 3*(N+1)*16 groups of 8 features
    if (gid >= 3 * (N_NODES + 1) * 16) return;
    int g = gid / ((N_NODES + 1) * 16);
    int loc = gid - g * (N_NODES + 1) * 16;
    int n = loc >> 4, c = loc & 15;
    uchar_t* outp = xs3 + (size_t)g * GSTRIDE + (size_t)n * 128 + c * 8;
    if (n == N_NODES) {                          // dummy zero row
        *(uint2*)outp = make_uint2(0u, 0u);
        return;
    }
    int d = deg_out[g * N_NODES + n]; if (d < 1) d = 1;
    const float* x = (g == 0) ? x0 : ((g == 1) ? x1 : x2);
    float s = rsqrtf((float)d) * 16.f;           // x16 exact, undone in gather
    const float4* xp = (const float4*)(x + n * 128 + c * 8);
    float4 v0 = xp[0], v1 = xp[1];
    uint2 o;
    o.x = f8pack4(v0.x * s, v0.y * s, v0.z * s, v0.w * s);
    o.y = f8pack4(v1.x * s, v1.y * s, v1.z * s, v1.w * s);
    *(uint2*)outp = o;
}

// ---------------- pack W into B-fragment layout (bf16), once ----------------
__global__ void k_prepW(const float* __restrict__ W, ushort_t* __restrict__ Wp) {
    int gid = blockIdx.x * 256 + threadIdx.x;   // NTILES*4*64 = 4864 groups
    if (gid >= NTILES * 4 * 64) return;
    int ct   = gid >> 8;
    int rem  = gid & 255;
    int kk   = rem >> 6;
    int lane = rem & 63;
    int col   = ct * 16 + (lane & 15);
    int kbase = kk * 32 + (lane >> 4) * 8;
    uint_t o[4];
    #pragma unroll
    for (int p = 0; p < 4; p++) {
        float f0 = W[(kbase + 2 * p)     * HID_F + col];
        float f1 = W[(kbase + 2 * p + 1) * HID_F + col];
        o[p] = packbf2(f0, f1);
    }
    *(uint4*)(Wp + gid * 8) = make_uint4(o[0], o[1], o[2], o[3]);
}

// ---------------- fused paired-row gather (fp8 dword loads) + MFMA GEMM ----------------
#define TSTRIDE 136   // 128 + 8 bf16 pad
__global__ __launch_bounds__(256, 4) void k_gg(const uchar_t* __restrict__ xs3,
                                               const int* __restrict__ row_off,
                                               const int* __restrict__ deg_in,
                                               const ushort_t* __restrict__ csr16,
                                               const ushort_t* __restrict__ Wp,
                                               const float* __restrict__ bias,
                                               float* __restrict__ gsum) {
    __shared__ ushort_t t_s[64 * TSTRIDE];          // 17408 B
    __shared__ ushort_t idx_s[4 * 16 * IDXS];       // 8192 B
    __shared__ float b_s[HID_F];
    __shared__ float wred[4];

    int tid = threadIdx.x, lane = tid & 63, wv = tid >> 6;
    int bid = blockIdx.x;
    int g = bid / NTB;
    int tile = bid - g * NTB;
    int n0 = tile * 64;
    int nfirst = n0 + wv * 16;
    bool wvalid = (nfirst + 16 <= N_NODES);   // 50000 % 64 == 16: waves all-valid or all-invalid

    const uchar_t* xb = xs3 + (size_t)g * GSTRIDE;
    const int* ro = row_off + g * N_NODES;
    const int* di = deg_in + g * N_NODES;

    if (tid < HID_F / 4) ((float4*)b_s)[tid] = ((const float4*)bias)[tid];

    int offv = 0, degv = 0;
    if (wvalid) {
        int node_l = nfirst + (lane & 15);
        offv = ro[node_l];        // lane l holds row (l & 15)
        degv = di[node_l];
    }

    int half = lane >> 5;               // 0: row A of pair, 1: row B
    int feat_off = (lane & 31) * 4;     // 4 fp8 features per lane

    if (wvalid) {
        // ---- stage indices: 4 lanes per row, strided copy ----
        {
            int row = lane >> 2, t4 = lane & 3;
            int o_r = __shfl(offv, row);
            int d_r = __shfl(degv, row);
            int dcap = d_r < IDXS ? d_r : IDXS;
            ushort_t* dst = idx_s + (wv * 16 + row) * IDXS;
            for (int j = t4; j < dcap; j += 4) dst[j] = csr16[o_r + j];
        }
        // ---- pad each row to its pair bound with DUMMY ----
        if (lane < 16) {
            int d_r = degv;
            int d_p = __shfl(degv, lane ^ 1);
            int mx = d_r > d_p ? d_r : d_p;
            int bnd = (mx + 7) & ~7; if (bnd > IDXS) bnd = IDXS;
            int st = d_r < IDXS ? d_r : IDXS;
            ushort_t* dst = idx_s + (wv * 16 + lane) * IDXS;
            for (int j = st; j < bnd; j++) dst[j] = DUMMY;
        }

        #pragma unroll 2
        for (int pg = 0; pg < 2; pg++) {
            int b_k[4], dm_k[4];
            #pragma unroll
            for (int k = 0; k < 4; k++) {
                int da = __builtin_amdgcn_readlane(degv, pg * 8 + 2 * k);
                int db = __builtin_amdgcn_readlane(degv, pg * 8 + 2 * k + 1);
                int mx = da > db ? da : db;
                dm_k[k] = mx;
                int bnd = (mx + 7) & ~7; if (bnd > IDXS) bnd = IDXS;
                b_k[k] = bnd;
            }
            int gmax = b_k[0];
            if (b_k[1] > gmax) gmax = b_k[1];
            if (b_k[2] > gmax) gmax = b_k[2];
            if (b_k[3] > gmax) gmax = b_k[3];

            float a[4][4] = {{0.f,0.f,0.f,0.f},{0.f,0.f,0.f,0.f},{0.f,0.f,0.f,0.f},{0.f,0.f,0.f,0.f}};

            for (int j = 0; j < gmax; j += 8) {
                uint_t vv[4][8];
                ushort8_t inds[4];
                // issue all loads first (up to 32 outstanding, 256 B each)
                #pragma unroll
                for (int k = 0; k < 4; k++) {
                    if (j < b_k[k]) {
                        inds[k] = *(const ushort8_t*)(idx_s + (wv * 16 + pg * 8 + 2 * k + half) * IDXS + j);
                        #pragma unroll
                        for (int e = 0; e < 8; e++) {
                            int idx = (int)inds[k][e];
                            vv[k][e] = *(const uint_t*)(xb + (size_t)idx * 128 + feat_off);
                        }
                    }
                }
                // consume
                #pragma unroll
                for (int k = 0; k < 4; k++) {
                    if (j < b_k[k]) {
                        #pragma unroll
                        for (int e = 0; e < 8; e++) {
                            uint_t v = vv[k][e];
                            floatx2 lo = f8dec2lo(v);
                            floatx2 hi = f8dec2hi(v);
                            a[k][0] += lo.x; a[k][1] += lo.y;
                            a[k][2] += hi.x; a[k][3] += hi.y;
                        }
                    }
                }
            }

            // epilogue per pair (+ never-taken tail for deg > IDXS)
            #pragma unroll
            for (int k = 0; k < 4; k++) {
                int r = pg * 8 + 2 * k + half;      // lane's row within wave
                int d_r = __shfl(degv, r);
                if (dm_k[k] > IDXS) {                // astronomically rare; correctness path
                    int o_r = __shfl(offv, r);
                    for (int j = IDXS; j < dm_k[k]; j++) {
                        int pc = j < d_r ? j : (d_r > 0 ? d_r - 1 : 0);
                        int idx = (int)csr16[o_r + pc];
                        uint_t v = *(const uint_t*)(xb + (size_t)idx * 128 + feat_off);
                        if (j >= d_r) v = 0u;
                        floatx2 lo = f8dec2lo(v);
                        floatx2 hi = f8dec2hi(v);
                        a[k][0] += lo.x; a[k][1] += lo.y;
                        a[k][2] += hi.x; a[k][3] += hi.y;
                    }
                }
                int dd = d_r < 1 ? 1 : d_r;
                float sc = rsqrtf((float)dd) * 0.0625f;   // undo x16 prescale
                uint2 o;
                o.x = packbf2(a[k][0] * sc, a[k][1] * sc);
                o.y = packbf2(a[k][2] * sc, a[k][3] * sc);
                *(uint2*)((char*)t_s + (size_t)(wv * 16 + r) * TSTRIDE * 2 + (lane & 31) * 8) = o;
            }
        }
    } else {
        for (int r = 0; r < 16; r++)
            *(uint2*)((char*)t_s + (size_t)(wv * 16 + r) * TSTRIDE * 2 + (lane & 31) * 8) = make_uint2(0u, 0u);
    }
    __syncthreads();

    int m = lane & 15, quad = lane >> 4;
    const ushort_t* ap = &t_s[(wv * 16 + m) * TSTRIDE + quad * 8];
    short8_t a0f = *(const short8_t*)(ap);
    short8_t a1f = *(const short8_t*)(ap + 32);
    short8_t a2f = *(const short8_t*)(ap + 64);
    short8_t a3f = *(const short8_t*)(ap + 96);

    float ssum = 0.f;
    int row_base = n0 + wv * 16 + quad * 4;

    for (int ct = 0; ct < NTILES; ct++) {
        const ushort_t* w0 = Wp + ((ct * 4) * 64 + lane) * 8;
        short8_t b0 = *(const short8_t*)(w0);
        short8_t b1 = *(const short8_t*)(w0 + 512);
        short8_t b2 = *(const short8_t*)(w0 + 1024);
        short8_t b3 = *(const short8_t*)(w0 + 1536);
        floatx4 acc = {0.f, 0.f, 0.f, 0.f};
        acc = __builtin_amdgcn_mfma_f32_16x16x32_bf16(a0f, b0, acc, 0, 0, 0);
        acc = __builtin_amdgcn_mfma_f32_16x16x32_bf16(a1f, b1, acc, 0, 0, 0);
        acc = __builtin_amdgcn_mfma_f32_16x16x32_bf16(a2f, b2, acc, 0, 0, 0);
        acc = __builtin_amdgcn_mfma_f32_16x16x32_bf16(a3f, b3, acc, 0, 0, 0);
        float bv = b_s[ct * 16 + m];
        #pragma unroll
        for (int r = 0; r < 4; r++) {
            if (row_base + r < N_NODES) {
                float y = acc[r] + bv;        // C/D: col=lane&15, row=quad*4+r
                ssum += fmaxf(y, 0.f);
            }
        }
    }

    #pragma unroll
    for (int o = 32; o; o >>= 1) ssum += __shfl_down(ssum, o, 64);
    if (lane == 0) wred[wv] = ssum;
    __syncthreads();
    if (tid == 0) atomicAdd(gsum, wred[0] + wred[1] + wred[2] + wred[3]);
}

// ---------------- finalize ----------------
__global__ void k_finalize(const float* __restrict__ gsum, float* __restrict__ out) {
    out[0] = gsum[0] * (1.0f / (3.0f * N_NODES * HID_F));
}

extern "C" void kernel_launch(void* const* d_in, const int* in_sizes, int n_in,
                              void* d_out, int out_size, void* d_ws, size_t ws_size,
                              hipStream_t stream) {
    const float* x0 = (const float*)d_in[0];
    const float* x1 = (const float*)d_in[1];
    const float* x2 = (const float*)d_in[2];
    const int* srcs[3] = {(const int*)d_in[3], (const int*)d_in[5], (const int*)d_in[7]};
    const int* dsts[3] = {(const int*)d_in[4], (const int*)d_in[6], (const int*)d_in[8]};
    const float* W = (const float*)d_in[9];
    const float* b = (const float*)d_in[10];

    char* ws = (char*)d_ws;
    int* deg_out       = (int*)(ws + 0);               // 600,000
    int* deg_in        = (int*)(ws + 600000);          // 600,000
    int* row_off       = (int*)(ws + 1200000);         // 600,000
    ushort_t* csr16    = (ushort_t*)(ws + 1800000);    // 5,419,008 -> 7,219,008 (pad to 7,219,072)
    int* cnt_d         = (int*)(ws + 7219072);         // 115,248 (3*196*49)
    int* cnt_sA        = (int*)(ws + 7334320);         // 115,248 -> 7,449,568 (pad to 7,449,600)
    uint_t* region_d   = (uint_t*)(ws + 7449600);      // 18,439,680 -> 25,889,280 (dead after k_csr)
    ushort_t* region_s = (ushort_t*)(ws + 25889280);   // 9,219,840 -> 35,109,120 (dead after k_csr)
    uchar_t* xs3       = (uchar_t*)(ws + 7449600);     // 19,200,384 fp8 (overlays regions)
    ushort_t* Wp       = (ushort_t*)(ws + 35109120);   // 77,824
    float* gsum        = (float*)(ws + 35186944);      // 4

    hipMemsetAsync(gsum, 0, 4, stream);

    k_prepW<<<(NTILES * 4 * 64 + 255) / 256, 256, 0, stream>>>(W, Wp);
    k_bucket<<<3 * NCH, 256, 0, stream>>>(
        srcs[0], dsts[0], srcs[1], dsts[1], srcs[2], dsts[2],
        cnt_d, cnt_sA, region_d, region_s);
    k_csr<<<2 * 3 * NBK, 256, 0, stream>>>(
        region_d, region_s, cnt_d, cnt_sA, row_off, deg_in, deg_out, csr16);
    k_prescale_all<<<(3 * (N_NODES + 1) * 16 + 255) / 256, 256, 0, stream>>>(
        x0, x1, x2, deg_out, xs3);
    k_gg<<<3 * NTB, 256, 0, stream>>>(xs3, row_off, deg_in, csr16, Wp, b, gsum);
    k_finalize<<<1, 1, 0, stream>>>(gsum, (float*)d_out);
}

// Round 10
// 246.710 us; speedup vs baseline: 1.3528x; 1.1848x over previous
//
#include <hip/hip_runtime.h>

#define N_NODES 50000
#define N_EDGES 800000
#define IN_F    128
#define HID_F   304
#define NTILES  19      // 304 / 16
#define NBK     49      // buckets per graph (1024 nodes each)
#define BKN     1024    // nodes per bucket
#define CAP_B   18432   // csr16 entries per bucket (mean 16384, sigma 127, +16 sigma)
#define CHUNK   4096    // edges per phase-A block
#define NCH     196     // chunks per graph
#define CAP_C   160     // slots per (chunk, bucket) cell: mean 84, sigma 9.1, +8.4 sigma
#define NQ      4       // quarters per bucket for k_hist
#define CPQ     49      // cells per quarter (NCH / NQ)
#define NTB     782     // ceil(50000 / 64) node tiles per graph
#define IDXS    64      // staged indices per row in k_gg
#define DUMMY   ((ushort_t)N_NODES)            // index of the zero row
#define GSTRIDE ((size_t)(N_NODES + 1) * 128)  // fp8 bytes per graph incl. dummy row

typedef unsigned int   uint_t;
typedef unsigned short ushort_t;
typedef unsigned char  uchar_t;
typedef __attribute__((ext_vector_type(8))) short          short8_t;
typedef __attribute__((ext_vector_type(8))) unsigned short ushort8_t;
typedef __attribute__((ext_vector_type(4))) float          floatx4;
typedef __attribute__((ext_vector_type(2))) float          floatx2;

__device__ inline float bf2f(uint_t h) {
    uint_t u = h << 16; float f; __builtin_memcpy(&f, &u, 4); return f;
}
__device__ inline ushort_t f2bf(float f) {
    uint_t u; __builtin_memcpy(&u, &f, 4);
    uint_t r = u + 0x7fffu + ((u >> 16) & 1u);   // RTNE
    return (ushort_t)(r >> 16);
}
__device__ inline uint_t packbf2(float a, float b) {
    return (uint_t)f2bf(a) | ((uint_t)f2bf(b) << 16);
}

// ---- fp8 e4m3 (OCP) encode/decode, HW builtins with SW fallback ----
__device__ inline uint_t f8enc1(float f) {
    uint_t u; __builtin_memcpy(&u, &f, 4);
    uint_t s = (u >> 24) & 0x80u;
    float a = fabsf(f);
    if (a >= 448.f) return s | 0x7Eu;
    uint_t mag = u & 0x7fffffffu;
    uint_t r = mag + 0x7ffffu + ((mag >> 20) & 1u);
    int e8 = (int)(r >> 23) - 120;
    if (e8 <= 0) { int k = (int)rintf(a * 512.f); return s | (uint_t)k; }
    if (e8 > 15) return s | 0x7Eu;
    return s | ((uint_t)e8 << 3) | ((r >> 20) & 7u);
}
__device__ inline float f8dec1(uint_t b) {
    uint_t s = (b & 0x80u) << 24;
    uint_t e = (b >> 3) & 0xFu, m = b & 7u;
    uint_t bits;
    if (e == 0) {
        float v = (float)m * 0.001953125f;
        uint_t vb; __builtin_memcpy(&vb, &v, 4);
        bits = vb | s;
    } else {
        bits = s | ((e + 120u) << 23) | (m << 20);
    }
    float f; __builtin_memcpy(&f, &bits, 4); return f;
}
__device__ inline uint_t f8pack4(float a, float b, float c, float d) {
#if __has_builtin(__builtin_amdgcn_cvt_pk_fp8_f32)
    int v = __builtin_amdgcn_cvt_pk_fp8_f32(a, b, 0, false);
    v = __builtin_amdgcn_cvt_pk_fp8_f32(c, d, v, true);
    return (uint_t)v;
#else
    return f8enc1(a) | (f8enc1(b) << 8) | (f8enc1(c) << 16) | (f8enc1(d) << 24);
#endif
}
__device__ inline floatx2 f8dec2lo(uint_t v) {
#if __has_builtin(__builtin_amdgcn_cvt_pk_f32_fp8)
    return __builtin_amdgcn_cvt_pk_f32_fp8((int)v, false);
#else
    floatx2 r; r.x = f8dec1(v & 0xffu); r.y = f8dec1((v >> 8) & 0xffu); return r;
#endif
}
__device__ inline floatx2 f8dec2hi(uint_t v) {
#if __has_builtin(__builtin_amdgcn_cvt_pk_f32_fp8)
    return __builtin_amdgcn_cvt_pk_f32_fp8((int)v, true);
#else
    floatx2 r; r.x = f8dec1((v >> 16) & 0xffu); r.y = f8dec1((v >> 24) & 0xffu); return r;
#endif
}

// ---------------- phase A: fixed-slot partition (no hist pass, no global atomics) ----------------
__global__ __launch_bounds__(256) void k_bucket(
        const int* __restrict__ s0, const int* __restrict__ d0,
        const int* __restrict__ s1, const int* __restrict__ d1,
        const int* __restrict__ s2, const int* __restrict__ d2,
        int* __restrict__ cnt_d, int* __restrict__ cnt_sA,
        uint_t* __restrict__ region_d, ushort_t* __restrict__ region_s) {
    __shared__ int lcur_d[NBK], lcur_s[NBK];
    int tid = threadIdx.x;
    int g = blockIdx.x / NCH;
    int chunk = blockIdx.x - g * NCH;
    const int* sp = (g == 0) ? s0 : ((g == 1) ? s1 : s2);
    const int* dp = (g == 0) ? d0 : ((g == 1) ? d1 : d2);
    int base = chunk * CHUNK;
    int cnt = N_EDGES - base; if (cnt > CHUNK) cnt = CHUNK;
    int cell0 = (g * NCH + chunk) * NBK;

    if (tid < NBK) { lcur_d[tid] = 0; lcur_s[tid] = 0; }
    __syncthreads();
    for (int i = tid; i < cnt; i += 256) {
        int d = dp[base + i];
        int s = sp[base + i];
        int bd = d >> 10;
        int slot = atomicAdd(&lcur_d[bd], 1);
        if (slot < CAP_C)
            region_d[(size_t)(cell0 + bd) * CAP_C + slot] = (uint_t)s | ((uint_t)(d & 1023) << 16);
        int bs = s >> 10;
        int slot2 = atomicAdd(&lcur_s[bs], 1);
        if (slot2 < CAP_C)
            region_s[(size_t)(cell0 + bs) * CAP_C + slot2] = (ushort_t)(s & 1023);
    }
    __syncthreads();
    if (tid < NBK) {
        int cd = lcur_d[tid]; if (cd > CAP_C) cd = CAP_C;
        int cs = lcur_s[tid]; if (cs > CAP_C) cs = CAP_C;
        cnt_d [cell0 + tid] = cd;
        cnt_sA[cell0 + tid] = cs;
    }
}

// ---------------- phase B1: partial histograms per (bucket, quarter) ----------------
// grid: [0, 3*NBK*NQ) = dst quarters -> hist_part; [3*NBK*NQ, 2*3*NBK*NQ) = src quarters -> deg_part
__global__ __launch_bounds__(256) void k_hist(const uint_t* __restrict__ region_d,
                                              const ushort_t* __restrict__ region_s,
                                              const int* __restrict__ cnt_d,
                                              const int* __restrict__ cnt_sA,
                                              int* __restrict__ hist_part,
                                              int* __restrict__ deg_part) {
    __shared__ int hist2[2 * BKN];     // dual copies to halve LDS-atomic bank conflicts
    __shared__ int cnts_s[CPQ];
    int tid = threadIdx.x, lane = tid & 63, wv = tid >> 6;
    int bid = blockIdx.x;
    bool dst_part = (bid < 3 * NBK * NQ);
    int lb = dst_part ? bid : bid - 3 * NBK * NQ;
    int g = lb / (NBK * NQ);
    int r2 = lb - g * (NBK * NQ);
    int b = r2 / NQ;
    int q = r2 - b * NQ;

    for (int i = tid; i < 2 * BKN; i += 256) hist2[i] = 0;
    if (tid < CPQ)
        cnts_s[tid] = (dst_part ? cnt_d : cnt_sA)[(g * NCH + q * CPQ + tid) * NBK + b];
    __syncthreads();

    int* hist = hist2 + (wv & 1) * BKN;
    if (dst_part) {
        for (int cc = wv; cc < CPQ; cc += 4) {
            const uint_t* src = region_d + (size_t)((g * NCH + q * CPQ + cc) * NBK + b) * CAP_C;
            int n = cnts_s[cc];
            for (int i = lane; i < n; i += 64)
                atomicAdd(&hist[src[i] >> 16], 1);
        }
    } else {
        for (int cc = wv; cc < CPQ; cc += 4) {
            const ushort_t* src = region_s + (size_t)((g * NCH + q * CPQ + cc) * NBK + b) * CAP_C;
            int n = cnts_s[cc];
            for (int i = lane; i < n; i += 64)
                atomicAdd(&hist[src[i]], 1);
        }
    }
    __syncthreads();
    int* out = (dst_part ? hist_part : deg_part) + ((g * NBK + b) * NQ + q) * BKN;
    for (int i = tid; i < BKN; i += 256)
        out[i] = hist2[i] + hist2[BKN + i];
}

// ---------------- phase B2: scan + scatter into bucket-local CSR (1024 threads, 16 waves) ----------------
__global__ __launch_bounds__(1024) void k_scat(const uint_t* __restrict__ region_d,
                                               const int* __restrict__ cnt_d,
                                               const int* __restrict__ hist_part,
                                               int* __restrict__ row_off,
                                               int* __restrict__ deg_in,
                                               ushort_t* __restrict__ csr16) {
    __shared__ int off_s[BKN];
    __shared__ int cnts_s[NCH];
    __shared__ int wsum[16];
    int tid = threadIdx.x, lane = tid & 63, wv = tid >> 6;
    int g = blockIdx.x / NBK;
    int b = blockIdx.x - g * NBK;
    int node0 = b * BKN;
    int bucket_base = (g * NBK + b) * CAP_B;

    // summed histogram (coalesced partial reads)
    const int* hp = hist_part + (g * NBK + b) * NQ * BKN;
    int h = hp[tid] + hp[BKN + tid] + hp[2 * BKN + tid] + hp[3 * BKN + tid];

    // exclusive scan over 1024 bins (1 per thread)
    int inc = h;
    #pragma unroll
    for (int o = 1; o < 64; o <<= 1) {
        int u = __shfl_up(inc, o, 64);
        if (lane >= o) inc += u;
    }
    if (lane == 63) wsum[wv] = inc;
    if (tid < NCH) cnts_s[tid] = cnt_d[(g * NCH + tid) * NBK + b];
    __syncthreads();
    if (wv == 0) {
        int t2 = (lane < 16) ? wsum[lane] : 0;
        #pragma unroll
        for (int o = 1; o < 16; o <<= 1) {
            int u = __shfl_up(t2, o, 64);
            if (lane >= o) t2 += u;
        }
        if (lane < 16) wsum[lane] = t2;
    }
    __syncthreads();
    int excl = ((wv > 0) ? wsum[wv - 1] : 0) + inc - h;
    off_s[tid] = excl;
    if (node0 + tid < N_NODES) {
        row_off[g * N_NODES + node0 + tid] = bucket_base + excl;
        deg_in [g * N_NODES + node0 + tid] = h;
    }
    __syncthreads();

    // scatter: 196 cells over 16 waves (12-13 each)
    for (int cc = wv; cc < NCH; cc += 16) {
        const uint_t* src = region_d + (size_t)((g * NCH + cc) * NBK + b) * CAP_C;
        int n = cnts_s[cc];
        for (int i = lane; i < n; i += 64) {
            uint_t w = src[i];
            int pos = atomicAdd(&off_s[w >> 16], 1);
            csr16[bucket_base + pos] = (ushort_t)(w & 0xffffu);
        }
    }
}

// ---------------- prescale (all 3 graphs + dummy rows): xs = fp8(x * inv_out * 16) ----------------
__global__ void k_prescale_all(const float* __restrict__ x0, const float* __restrict__ x1,
                               const float* __restrict__ x2, const int* __restrict__ deg_part,
                               uchar_t* __restrict__ xs3) {
    int gid = blockIdx.x * 256 + threadIdx.x;   // 3*(N+1)*16 groups of 8 features
    if (gid >= 3 * (N_NODES + 1) * 16) return;
    int g = gid / ((N_NODES + 1) * 16);
    int loc = gid - g * (N_NODES + 1) * 16;
    int n = loc >> 4, c = loc & 15;
    uchar_t* outp = xs3 + (size_t)g * GSTRIDE + (size_t)n * 128 + c * 8;
    if (n == N_NODES) {                          // dummy zero row
        *(uint2*)outp = make_uint2(0u, 0u);
        return;
    }
    int bb = n >> 10, nl = n & 1023;
    const int* dp = deg_part + ((g * NBK + bb) * NQ) * BKN + nl;
    int d = dp[0] + dp[BKN] + dp[2 * BKN] + dp[3 * BKN];
    if (d < 1) d = 1;
    const float* x = (g == 0) ? x0 : ((g == 1) ? x1 : x2);
    float s = rsqrtf((float)d) * 16.f;           // x16 exact, undone in gather
    const float4* xp = (const float4*)(x + n * 128 + c * 8);
    float4 v0 = xp[0], v1 = xp[1];
    uint2 o;
    o.x = f8pack4(v0.x * s, v0.y * s, v0.z * s, v0.w * s);
    o.y = f8pack4(v1.x * s, v1.y * s, v1.z * s, v1.w * s);
    *(uint2*)outp = o;
}

// ---------------- pack W into B-fragment layout (bf16), once ----------------
__global__ void k_prepW(const float* __restrict__ W, ushort_t* __restrict__ Wp) {
    int gid = blockIdx.x * 256 + threadIdx.x;   // NTILES*4*64 = 4864 groups
    if (gid >= NTILES * 4 * 64) return;
    int ct   = gid >> 8;
    int rem  = gid & 255;
    int kk   = rem >> 6;
    int lane = rem & 63;
    int col   = ct * 16 + (lane & 15);
    int kbase = kk * 32 + (lane >> 4) * 8;
    uint_t o[4];
    #pragma unroll
    for (int p = 0; p < 4; p++) {
        float f0 = W[(kbase + 2 * p)     * HID_F + col];
        float f1 = W[(kbase + 2 * p + 1) * HID_F + col];
        o[p] = packbf2(f0, f1);
    }
    *(uint4*)(Wp + gid * 8) = make_uint4(o[0], o[1], o[2], o[3]);
}

// ---------------- fused paired-row gather (fp8 dword loads) + MFMA GEMM ----------------
#define TSTRIDE 136   // 128 + 8 bf16 pad
__global__ __launch_bounds__(256, 4) void k_gg(const uchar_t* __restrict__ xs3,
                                               const int* __restrict__ row_off,
                                               const int* __restrict__ deg_in,
                                               const ushort_t* __restrict__ csr16,
                                               const ushort_t* __restrict__ Wp,
                                               const float* __restrict__ bias,
                                               float* __restrict__ gsum) {
    __shared__ ushort_t t_s[64 * TSTRIDE];          // 17408 B
    __shared__ ushort_t idx_s[4 * 16 * IDXS];       // 8192 B
    __shared__ float b_s[HID_F];
    __shared__ float wred[4];

    int tid = threadIdx.x, lane = tid & 63, wv = tid >> 6;
    int bid = blockIdx.x;
    int g = bid / NTB;
    int tile = bid - g * NTB;
    int n0 = tile * 64;
    int nfirst = n0 + wv * 16;
    bool wvalid = (nfirst + 16 <= N_NODES);   // 50000 % 64 == 16: waves all-valid or all-invalid

    const uchar_t* xb = xs3 + (size_t)g * GSTRIDE;
    const int* ro = row_off + g * N_NODES;
    const int* di = deg_in + g * N_NODES;

    if (tid < HID_F / 4) ((float4*)b_s)[tid] = ((const float4*)bias)[tid];

    int offv = 0, degv = 0;
    if (wvalid) {
        int node_l = nfirst + (lane & 15);
        offv = ro[node_l];        // lane l holds row (l & 15)
        degv = di[node_l];
    }

    int half = lane >> 5;               // 0: row A of pair, 1: row B
    int feat_off = (lane & 31) * 4;     // 4 fp8 features per lane

    if (wvalid) {
        // ---- stage indices: 4 lanes per row, strided copy ----
        {
            int row = lane >> 2, t4 = lane & 3;
            int o_r = __shfl(offv, row);
            int d_r = __shfl(degv, row);
            int dcap = d_r < IDXS ? d_r : IDXS;
            ushort_t* dst = idx_s + (wv * 16 + row) * IDXS;
            for (int j = t4; j < dcap; j += 4) dst[j] = csr16[o_r + j];
        }
        // ---- pad each row to its pair bound with DUMMY ----
        if (lane < 16) {
            int d_r = degv;
            int d_p = __shfl(degv, lane ^ 1);
            int mx = d_r > d_p ? d_r : d_p;
            int bnd = (mx + 7) & ~7; if (bnd > IDXS) bnd = IDXS;
            int st = d_r < IDXS ? d_r : IDXS;
            ushort_t* dst = idx_s + (wv * 16 + lane) * IDXS;
            for (int j = st; j < bnd; j++) dst[j] = DUMMY;
        }

        #pragma unroll 2
        for (int pg = 0; pg < 2; pg++) {
            int b_k[4], dm_k[4];
            #pragma unroll
            for (int k = 0; k < 4; k++) {
                int da = __builtin_amdgcn_readlane(degv, pg * 8 + 2 * k);
                int db = __builtin_amdgcn_readlane(degv, pg * 8 + 2 * k + 1);
                int mx = da > db ? da : db;
                dm_k[k] = mx;
                int bnd = (mx + 7) & ~7; if (bnd > IDXS) bnd = IDXS;
                b_k[k] = bnd;
            }
            int gmax = b_k[0];
            if (b_k[1] > gmax) gmax = b_k[1];
            if (b_k[2] > gmax) gmax = b_k[2];
            if (b_k[3] > gmax) gmax = b_k[3];

            float a[4][4] = {{0.f,0.f,0.f,0.f},{0.f,0.f,0.f,0.f},{0.f,0.f,0.f,0.f},{0.f,0.f,0.f,0.f}};

            for (int j = 0; j < gmax; j += 8) {
                uint_t vv[4][8];
                ushort8_t inds[4];
                // issue all loads first (up to 32 outstanding, 256 B each)
                #pragma unroll
                for (int k = 0; k < 4; k++) {
                    if (j < b_k[k]) {
                        inds[k] = *(const ushort8_t*)(idx_s + (wv * 16 + pg * 8 + 2 * k + half) * IDXS + j);
                        #pragma unroll
                        for (int e = 0; e < 8; e++) {
                            int idx = (int)inds[k][e];
                            vv[k][e] = *(const uint_t*)(xb + (size_t)idx * 128 + feat_off);
                        }
                    }
                }
                // consume
                #pragma unroll
                for (int k = 0; k < 4; k++) {
                    if (j < b_k[k]) {
                        #pragma unroll
                        for (int e = 0; e < 8; e++) {
                            uint_t v = vv[k][e];
                            floatx2 lo = f8dec2lo(v);
                            floatx2 hi = f8dec2hi(v);
                            a[k][0] += lo.x; a[k][1] += lo.y;
                            a[k][2] += hi.x; a[k][3] += hi.y;
                        }
                    }
                }
            }

            // epilogue per pair (+ never-taken tail for deg > IDXS)
            #pragma unroll
            for (int k = 0; k < 4; k++) {
                int r = pg * 8 + 2 * k + half;      // lane's row within wave
                int d_r = __shfl(degv, r);
                if (dm_k[k] > IDXS) {                // astronomically rare; correctness path
                    int o_r = __shfl(offv, r);
                    for (int j = IDXS; j < dm_k[k]; j++) {
                        int pc = j < d_r ? j : (d_r > 0 ? d_r - 1 : 0);
                        int idx = (int)csr16[o_r + pc];
                        uint_t v = *(const uint_t*)(xb + (size_t)idx * 128 + feat_off);
                        if (j >= d_r) v = 0u;
                        floatx2 lo = f8dec2lo(v);
                        floatx2 hi = f8dec2hi(v);
                        a[k][0] += lo.x; a[k][1] += lo.y;
                        a[k][2] += hi.x; a[k][3] += hi.y;
                    }
                }
                int dd = d_r < 1 ? 1 : d_r;
                float sc = rsqrtf((float)dd) * 0.0625f;   // undo x16 prescale
                uint2 o;
                o.x = packbf2(a[k][0] * sc, a[k][1] * sc);
                o.y = packbf2(a[k][2] * sc, a[k][3] * sc);
                *(uint2*)((char*)t_s + (size_t)(wv * 16 + r) * TSTRIDE * 2 + (lane & 31) * 8) = o;
            }
        }
    } else {
        for (int r = 0; r < 16; r++)
            *(uint2*)((char*)t_s + (size_t)(wv * 16 + r) * TSTRIDE * 2 + (lane & 31) * 8) = make_uint2(0u, 0u);
    }
    __syncthreads();

    int m = lane & 15, quad = lane >> 4;
    const ushort_t* ap = &t_s[(wv * 16 + m) * TSTRIDE + quad * 8];
    short8_t a0f = *(const short8_t*)(ap);
    short8_t a1f = *(const short8_t*)(ap + 32);
    short8_t a2f = *(const short8_t*)(ap + 64);
    short8_t a3f = *(const short8_t*)(ap + 96);

    float ssum = 0.f;
    int row_base = n0 + wv * 16 + quad * 4;

    for (int ct = 0; ct < NTILES; ct++) {
        const ushort_t* w0 = Wp + ((ct * 4) * 64 + lane) * 8;
        short8_t b0 = *(const short8_t*)(w0);
        short8_t b1 = *(const short8_t*)(w0 + 512);
        short8_t b2 = *(const short8_t*)(w0 + 1024);
        short8_t b3 = *(const short8_t*)(w0 + 1536);
        floatx4 acc = {0.f, 0.f, 0.f, 0.f};
        acc = __builtin_amdgcn_mfma_f32_16x16x32_bf16(a0f, b0, acc, 0, 0, 0);
        acc = __builtin_amdgcn_mfma_f32_16x16x32_bf16(a1f, b1, acc, 0, 0, 0);
        acc = __builtin_amdgcn_mfma_f32_16x16x32_bf16(a2f, b2, acc, 0, 0, 0);
        acc = __builtin_amdgcn_mfma_f32_16x16x32_bf16(a3f, b3, acc, 0, 0, 0);
        float bv = b_s[ct * 16 + m];
        #pragma unroll
        for (int r = 0; r < 4; r++) {
            if (row_base + r < N_NODES) {
                float y = acc[r] + bv;        // C/D: col=lane&15, row=quad*4+r
                ssum += fmaxf(y, 0.f);
            }
        }
    }

    #pragma unroll
    for (int o = 32; o; o >>= 1) ssum += __shfl_down(ssum, o, 64);
    if (lane == 0) wred[wv] = ssum;
    __syncthreads();
    if (tid == 0) atomicAdd(gsum, wred[0] + wred[1] + wred[2] + wred[3]);
}

// ---------------- finalize ----------------
__global__ void k_finalize(const float* __restrict__ gsum, float* __restrict__ out) {
    out[0] = gsum[0] * (1.0f / (3.0f * N_NODES * HID_F));
}

extern "C" void kernel_launch(void* const* d_in, const int* in_sizes, int n_in,
                              void* d_out, int out_size, void* d_ws, size_t ws_size,
                              hipStream_t stream) {
    const float* x0 = (const float*)d_in[0];
    const float* x1 = (const float*)d_in[1];
    const float* x2 = (const float*)d_in[2];
    const int* srcs[3] = {(const int*)d_in[3], (const int*)d_in[5], (const int*)d_in[7]};
    const int* dsts[3] = {(const int*)d_in[4], (const int*)d_in[6], (const int*)d_in[8]};
    const float* W = (const float*)d_in[9];
    const float* b = (const float*)d_in[10];

    char* ws = (char*)d_ws;
    int* deg_in        = (int*)(ws + 0);               // 600,000
    int* row_off       = (int*)(ws + 600000);          // 600,000
    ushort_t* csr16    = (ushort_t*)(ws + 1200000);    // 5,419,008 -> 6,619,008 (pad 6,619,136)
    int* cnt_d         = (int*)(ws + 6619136);         // 115,248 -> 6,734,384 (pad 6,734,592)
    int* cnt_sA        = (int*)(ws + 6734592);         // 115,248 -> 6,849,840 (pad 6,850,048)
    int* hist_part     = (int*)(ws + 6850048);         // 2,408,448 -> 9,258,496
    int* deg_part      = (int*)(ws + 9258496);         // 2,408,448 -> 11,666,944 (pad 11,667,456)
    uint_t* region_d   = (uint_t*)(ws + 11667456);     // 18,439,680 -> 30,107,136 (dead after k_scat)
    ushort_t* region_s = (ushort_t*)(ws + 30107136);   // 9,219,840 -> 39,326,976 (dead after k_hist)
    uchar_t* xs3       = (uchar_t*)(ws + 11667456);    // 19,200,384 fp8 (overlays regions)
    ushort_t* Wp       = (ushort_t*)(ws + 39326976);   // 77,824
    float* gsum        = (float*)(ws + 39404800);      // 4

    hipMemsetAsync(gsum, 0, 4, stream);

    k_prepW<<<(NTILES * 4 * 64 + 255) / 256, 256, 0, stream>>>(W, Wp);
    k_bucket<<<3 * NCH, 256, 0, stream>>>(
        srcs[0], dsts[0], srcs[1], dsts[1], srcs[2], dsts[2],
        cnt_d, cnt_sA, region_d, region_s);
    k_hist<<<2 * 3 * NBK * NQ, 256, 0, stream>>>(
        region_d, region_s, cnt_d, cnt_sA, hist_part, deg_part);
    k_scat<<<3 * NBK, 1024, 0, stream>>>(
        region_d, cnt_d, hist_part, row_off, deg_in, csr16);
    k_prescale_all<<<(3 * (N_NODES + 1) * 16 + 255) / 256, 256, 0, stream>>>(
        x0, x1, x2, deg_part, xs3);
    k_gg<<<3 * NTB, 256, 0, stream>>>(xs3, row_off, deg_in, csr16, Wp, b, gsum);
    k_finalize<<<1, 1, 0, stream>>>(gsum, (float*)d_out);
}